// Round 3
// baseline (1219.664 us; speedup 1.0000x reference)
//
#include <hip/hip_runtime.h>
#include <cstdint>

// Problem constants
#define Bb 4
#define Tt 4096
#define Cc 2048
#define Hh 16
#define Dh 128
#define BT (Bb * Tt)            // 16384 rows
#define NCHUNK 32
#define TCHUNK 128              // NCHUNK*TCHUNK == Tt
#define NCHAN (Bb * Cc)         // 8192 scan channels
#define NQKV 6144               // 3*Cc

typedef __bf16 bf16x8 __attribute__((ext_vector_type(8)));
typedef float f32x4 __attribute__((ext_vector_type(4)));
typedef unsigned short u16x8 __attribute__((ext_vector_type(8)));

__device__ __forceinline__ float bf2f(unsigned short u) {
  return __uint_as_float(((unsigned)u) << 16);
}
__device__ __forceinline__ unsigned short f2bf(float f) {
  unsigned u = __float_as_uint(f);
  u = u + 0x7fffu + ((u >> 16) & 1u);   // RNE
  return (unsigned short)(u >> 16);
}

// async global->LDS, 16B per lane; lds must be wave-uniform (HW writes base + lane*16)
__device__ __forceinline__ void async_copy16(void* lds, const void* gmem) {
  auto* lp = (__attribute__((address_space(3))) unsigned int*)(unsigned)(uintptr_t)(lds);
  auto* gp = (const __attribute__((address_space(1))) unsigned int*)(uintptr_t)(gmem);
  __builtin_amdgcn_global_load_lds(gp, lp, 16, 0, 0);
}

// ---------------- fp32 -> bf16 convert: 5 weight matrices into one packed buffer ----
// dst layout: [wq | wk | wv | wo | wg], each nW = Cc*Cc elements
__global__ __launch_bounds__(256) void cvt5_kernel(const float* __restrict__ Wq,
                                                   const float* __restrict__ Wk,
                                                   const float* __restrict__ Wv,
                                                   const float* __restrict__ Wo,
                                                   const float* __restrict__ Wg,
                                                   unsigned short* __restrict__ dst) {
  size_t idx4 = ((size_t)blockIdx.x * 256 + threadIdx.x) * 4;
  int region = (int)(idx4 >> 22);               // nW = 2^22
  size_t off = idx4 & ((1u << 22) - 1);
  const float* src;
  switch (region) {
    case 0: src = Wq; break;
    case 1: src = Wk; break;
    case 2: src = Wv; break;
    case 3: src = Wo; break;
    default: src = Wg; break;
  }
  float4 v = *(const float4*)(src + off);
  unsigned r0 = (unsigned)f2bf(v.x) | ((unsigned)f2bf(v.y) << 16);
  unsigned r1 = (unsigned)f2bf(v.z) | ((unsigned)f2bf(v.w) << 16);
  *(uint2*)(dst + idx4) = make_uint2(r0, r1);
}

// ---------------- depthwise causal conv K=4 + SiLU + x->bf16 ----------------
__global__ __launch_bounds__(256) void conv_kernel(const float* __restrict__ x,
                                                   const float* __restrict__ cw,
                                                   const float* __restrict__ cb,
                                                   unsigned short* __restrict__ xb,
                                                   unsigned short* __restrict__ xcb) {
  int idx = blockIdx.x * 256 + threadIdx.x;
  int cg = idx & 511;                 // Cc/4
  int rg = idx >> 9;                  // row group over BT/8
  int c = cg * 4;
  size_t bt0 = (size_t)rg * 8;
  int t0 = (int)(bt0 & (Tt - 1));
  const float* xp = x + bt0 * Cc + c;

  float4 w4[4];
#pragma unroll
  for (int u = 0; u < 4; u++) w4[u] = *(const float4*)(cw + (size_t)(c + u) * 4);
  float4 bias = *(const float4*)(cb + c);
  const float* bs = (const float*)&bias;

  float xr[11][4];                    // rows t0-3..t0+7
  if (t0 != 0) {
#pragma unroll
    for (int j = 0; j < 3; j++) {
      float4 p = *(const float4*)(xp - (size_t)(3 - j) * Cc);
      xr[j][0] = p.x; xr[j][1] = p.y; xr[j][2] = p.z; xr[j][3] = p.w;
    }
  } else {
#pragma unroll
    for (int j = 0; j < 3; j++)
#pragma unroll
      for (int u = 0; u < 4; u++) xr[j][u] = 0.f;
  }
#pragma unroll
  for (int i = 0; i < 8; i++) {
    float4 p = *(const float4*)(xp + (size_t)i * Cc);
    xr[3 + i][0] = p.x; xr[3 + i][1] = p.y; xr[3 + i][2] = p.z; xr[3 + i][3] = p.w;
    unsigned a0 = (unsigned)f2bf(p.x) | ((unsigned)f2bf(p.y) << 16);
    unsigned a1 = (unsigned)f2bf(p.z) | ((unsigned)f2bf(p.w) << 16);
    *(uint2*)(xb + (bt0 + i) * Cc + c) = make_uint2(a0, a1);
  }
#pragma unroll
  for (int i = 0; i < 8; i++) {
    unsigned short o[4];
#pragma unroll
    for (int u = 0; u < 4; u++) {
      const float* wf = (const float*)&w4[u];
      float a = bs[u];
#pragma unroll
      for (int j = 0; j < 4; j++) a += wf[3 - j] * xr[3 + i - j][u];
      float sig = 1.f / (1.f + expf(-a));
      o[u] = f2bf(a * sig);
    }
    unsigned q0 = (unsigned)o[0] | ((unsigned)o[1] << 16);
    unsigned q1 = (unsigned)o[2] | ((unsigned)o[3] << 16);
    *(uint2*)(xcb + (bt0 + i) * Cc + c) = make_uint2(q0, q1);
  }
}

// ---------------- 256x256-tile bf16 GEMM: C[M,N] = A[M,K] * B[N,K]^T ----------------
// 8 waves (2M x 4N), BK=32, 4-slot LDS ring staging t+2 while computing t.
// Software-pipelined fragment loads with COUNTED lgkmcnt:
//   phase A(t): stage(t+2) x4 VMEM; issue afB(t) x4 ds_read; barrier;
//               lgkmcnt(4) [afA/bf ready, afB in flight]; MFMA A; vmcnt(4); barrier
//   phase B(t): issue afA(t+1)+bf'(t+1) x8 ds_read (slot t+1, safe after vmcnt(4)+barrier);
//               barrier; lgkmcnt(8) [afB ready, 8 in flight]; MFMA B; barrier
// bf double-buffered via two NAMED arrays (no runtime reg indexing), loop 2x-unrolled.
// Bank swizzle (conflicts measured 0): slot s of row r stores logical slot s ^ ((r>>1)&3),
// applied on pre-swizzled global SOURCE + swizzled ds_read offsets.
// EPI: 1 = sigmoid(acc + bias[col]) bf16 store, 2 = fp32 store,
//      3 = fused qkv: bf16 store; rows l2-normalized per 128-col head group when n0 < 2*Cc
template <int EPI>
__global__ __launch_bounds__(512, 2) void gemm256(const unsigned short* __restrict__ A,
                                                  const unsigned short* __restrict__ B,
                                                  void* __restrict__ C,
                                                  const float* __restrict__ bias,
                                                  int M, int N, int K) {
  __shared__ unsigned short As[4][256 * 32];   // 64 KiB
  __shared__ unsigned short Bs[4][256 * 32];   // 64 KiB
  __shared__ float rowsq[256][4];              // 4 KiB

  const int tid = threadIdx.x;
  const int w = tid >> 6;        // wave 0..7
  const int lane = tid & 63;

  // T1: XCD-aware block swizzle (nwg % 8 == 0 for all our launches)
  const int nwg = gridDim.x * gridDim.y;
  const int flat = blockIdx.y * gridDim.x + blockIdx.x;
  const int cpx = nwg >> 3;
  const int swz = (flat & 7) * cpx + (flat >> 3);
  const int bx = swz % gridDim.x;
  const int by = swz / gridDim.x;
  const int m0 = bx * 256;
  const int n0 = by * 256;

  const int wr = w >> 2;         // 0..1 -> 128-row half
  const int wc = w & 3;          // 0..3 -> 64-col strip

  // ---- staging addresses (2 issues/thread per matrix per K-tile, 16 rows/issue) ----
  const int srow = lane >> 2;                                   // 0..15 within group
  const int scol = (((lane & 3) ^ ((lane >> 3) & 3)) << 3);     // swizzled source col (elems)
  const int r16 = w * 2;                                        // row-group of issue 0
  const unsigned short* Ag0 = A + (size_t)(m0 + r16 * 16 + srow) * K + scol;
  const unsigned short* Ag1 = Ag0 + (size_t)16 * K;
  const unsigned short* Bg0 = B + (size_t)(n0 + r16 * 16 + srow) * K + scol;
  const unsigned short* Bg1 = Bg0 + (size_t)16 * K;

  // ---- fragment read addressing (same swizzle) ----
  const int frow = lane & 15;
  const int cbs = ((((lane >> 4) << 4) ^ (((frow >> 1) & 3) << 4)) >> 1);  // short offset in row

  f32x4 acc[8][4] = {};
  const int NT = K >> 5;

  // prologue: stage K-tiles 0 and 1 fully; wait tile 0 (leave tile 1 in flight)
  {
    unsigned short* dA0 = &As[0][r16 * 512];
    unsigned short* dB0 = &Bs[0][r16 * 512];
    async_copy16(dA0, Ag0); async_copy16(dA0 + 512, Ag1);
    async_copy16(dB0, Bg0); async_copy16(dB0 + 512, Bg1);
    unsigned short* dA1 = &As[1][r16 * 512];
    unsigned short* dB1 = &Bs[1][r16 * 512];
    async_copy16(dA1, Ag0 + 32); async_copy16(dA1 + 512, Ag1 + 32);
    async_copy16(dB1, Bg0 + 32); async_copy16(dB1 + 512, Bg1 + 32);
  }
  asm volatile("s_waitcnt vmcnt(4)" ::: "memory");
  __builtin_amdgcn_s_barrier();

  bf16x8 afA[4], afB[4], bfq0[4], bfq1[4];
  {
    const unsigned short* as0 = &As[0][0] + wr * 4096 + cbs;
    const unsigned short* bs0 = &Bs[0][0] + wc * 2048 + cbs;
#pragma unroll
    for (int m = 0; m < 4; m++)
      afA[m] = __builtin_bit_cast(bf16x8, *(const u16x8*)(as0 + (m * 16 + frow) * 32));
#pragma unroll
    for (int n = 0; n < 4; n++)
      bfq0[n] = __builtin_bit_cast(bf16x8, *(const u16x8*)(bs0 + (n * 16 + frow) * 32));
  }

#define TILE_STEP(T, BFCUR, BFNXT)                                                         \
  do {                                                                                     \
    const int slot_ = (T) & 3;                                                             \
    const unsigned short* asw_ = &As[slot_][0] + wr * 4096 + cbs;                          \
    const bool pf_ = (T) + 2 < NT;                                                         \
    const bool rd_ = (T) + 1 < NT;                                                         \
    /* ---- phase A ---- */                                                                \
    if (pf_) {                                                                             \
      const int kpf_ = ((T) + 2) << 5;                                                     \
      unsigned short* dA_ = &As[((T) + 2) & 3][r16 * 512];                                 \
      unsigned short* dB_ = &Bs[((T) + 2) & 3][r16 * 512];                                 \
      async_copy16(dA_, Ag0 + kpf_); async_copy16(dA_ + 512, Ag1 + kpf_);                  \
      async_copy16(dB_, Bg0 + kpf_); async_copy16(dB_ + 512, Bg1 + kpf_);                  \
    }                                                                                      \
    _Pragma("unroll")                                                                      \
    for (int m = 0; m < 4; m++)                                                            \
      afB[m] = __builtin_bit_cast(bf16x8, *(const u16x8*)(asw_ + ((m + 4) * 16 + frow) * 32)); \
    __builtin_amdgcn_s_barrier();                                                          \
    asm volatile("s_waitcnt lgkmcnt(4)" ::: "memory");                                     \
    __builtin_amdgcn_sched_barrier(0);                                                     \
    __builtin_amdgcn_s_setprio(1);                                                         \
    _Pragma("unroll")                                                                      \
    for (int m = 0; m < 4; m++)                                                            \
      _Pragma("unroll")                                                                    \
      for (int n = 0; n < 4; n++)                                                          \
        acc[m][n] = __builtin_amdgcn_mfma_f32_16x16x32_bf16(afA[m], BFCUR[n], acc[m][n], 0, 0, 0); \
    __builtin_amdgcn_s_setprio(0);                                                         \
    if (pf_) asm volatile("s_waitcnt vmcnt(4)" ::: "memory");                              \
    else     asm volatile("s_waitcnt vmcnt(0)" ::: "memory");                              \
    __builtin_amdgcn_s_barrier();                                                          \
    /* ---- phase B ---- */                                                                \
    if (rd_) {                                                                             \
      const int slot1_ = ((T) + 1) & 3;                                                    \
      const unsigned short* asn_ = &As[slot1_][0] + wr * 4096 + cbs;                       \
      const unsigned short* bsn_ = &Bs[slot1_][0] + wc * 2048 + cbs;                       \
      _Pragma("unroll")                                                                    \
      for (int m = 0; m < 4; m++)                                                          \
        afA[m] = __builtin_bit_cast(bf16x8, *(const u16x8*)(asn_ + (m * 16 + frow) * 32)); \
      _Pragma("unroll")                                                                    \
      for (int n = 0; n < 4; n++)                                                          \
        BFNXT[n] = __builtin_bit_cast(bf16x8, *(const u16x8*)(bsn_ + (n * 16 + frow) * 32)); \
    }                                                                                      \
    __builtin_amdgcn_s_barrier();                                                          \
    if (rd_) asm volatile("s_waitcnt lgkmcnt(8)" ::: "memory");                            \
    else     asm volatile("s_waitcnt lgkmcnt(0)" ::: "memory");                            \
    __builtin_amdgcn_sched_barrier(0);                                                     \
    __builtin_amdgcn_s_setprio(1);                                                         \
    _Pragma("unroll")                                                                      \
    for (int m = 0; m < 4; m++)                                                            \
      _Pragma("unroll")                                                                    \
      for (int n = 0; n < 4; n++)                                                          \
        acc[m + 4][n] = __builtin_amdgcn_mfma_f32_16x16x32_bf16(afB[m], BFCUR[n], acc[m + 4][n], 0, 0, 0); \
    __builtin_amdgcn_s_setprio(0);                                                         \
    __builtin_amdgcn_s_barrier();                                                          \
  } while (0)

  for (int tt = 0; tt < NT; tt += 2) {
    TILE_STEP(tt, bfq0, bfq1);
    TILE_STEP(tt + 1, bfq1, bfq0);
  }
#undef TILE_STEP

  // ---------------- epilogue ----------------
  const int crow0 = (lane >> 4) * 4;
  const int ccol = lane & 15;

  float inv[8][4];
  const bool donorm = (EPI == 3) && (n0 < 2 * Cc);
  if (donorm) {
#pragma unroll
    for (int m = 0; m < 8; m++) {
#pragma unroll
      for (int r = 0; r < 4; r++) {
        float sq = 0.f;
#pragma unroll
        for (int n = 0; n < 4; n++) { float v = acc[m][n][r]; sq += v * v; }
        sq += __shfl_xor(sq, 1);
        sq += __shfl_xor(sq, 2);
        sq += __shfl_xor(sq, 4);
        sq += __shfl_xor(sq, 8);
        if (ccol == 0) rowsq[wr * 128 + m * 16 + crow0 + r][wc] = sq;
      }
    }
    __syncthreads();
#pragma unroll
    for (int m = 0; m < 8; m++)
#pragma unroll
      for (int r = 0; r < 4; r++) {
        int rloc = wr * 128 + m * 16 + crow0 + r;
        int g2 = (wc >> 1) * 2;
        float s = rowsq[rloc][g2] + rowsq[rloc][g2 + 1];
        inv[m][r] = 1.f / fmaxf(sqrtf(s), 1e-12f);
      }
  }

#pragma unroll
  for (int m = 0; m < 8; m++) {
#pragma unroll
    for (int n = 0; n < 4; n++) {
      int col = n0 + wc * 64 + n * 16 + ccol;
      float bv = (EPI == 1) ? bias[col] : 0.f;
#pragma unroll
      for (int r = 0; r < 4; r++) {
        int row = m0 + wr * 128 + m * 16 + crow0 + r;
        float v = acc[m][n][r];
        if (EPI == 1) v = 1.f / (1.f + expf(-(v + bv)));
        if (donorm) v *= inv[m][r];
        if (EPI == 2)
          ((float*)C)[(size_t)row * N + col] = v;
        else
          ((unsigned short*)C)[(size_t)row * N + col] = f2bf(v);
      }
    }
  }
}

// ---------------- chunked decayed scan (4 channels / thread) ----------------
__global__ __launch_bounds__(256) void scan_p1(const unsigned short* __restrict__ qkv,
                                               const float* __restrict__ gamma,
                                               float* __restrict__ carry) {
  int idx = blockIdx.x * 256 + threadIdx.x;     // [0, NCHUNK*NCHAN/4)
  int ch4 = idx & 2047;                         // NCHAN/4
  int chunk = idx >> 11;
  int b = ch4 >> 9;
  int c = (ch4 & 511) * 4;
  float g = gamma[c >> 7];
  const unsigned short* kb = qkv + ((size_t)(b * Tt + chunk * TCHUNK)) * NQKV + Cc + c;
  float L[4] = {0.f, 0.f, 0.f, 0.f};
#pragma unroll 4
  for (int t = 0; t < TCHUNK; t++) {
    const unsigned short* p = kb + (size_t)t * NQKV;
    uint2 kk = *(const uint2*)(p);
    uint2 vv = *(const uint2*)(p + Cc);
    L[0] = g * L[0] + bf2f((unsigned short)(kk.x & 0xffff)) * bf2f((unsigned short)(vv.x & 0xffff));
    L[1] = g * L[1] + bf2f((unsigned short)(kk.x >> 16))    * bf2f((unsigned short)(vv.x >> 16));
    L[2] = g * L[2] + bf2f((unsigned short)(kk.y & 0xffff)) * bf2f((unsigned short)(vv.y & 0xffff));
    L[3] = g * L[3] + bf2f((unsigned short)(kk.y >> 16))    * bf2f((unsigned short)(vv.y >> 16));
  }
  *(float4*)(carry + (size_t)chunk * NCHAN + b * Cc + c) = make_float4(L[0], L[1], L[2], L[3]);
}

__global__ __launch_bounds__(256) void scan_p2(float* __restrict__ carry,
                                               const float* __restrict__ gamma) {
  int ch = blockIdx.x * 256 + threadIdx.x;      // [0, NCHAN)
  int h = (ch & (Cc - 1)) >> 7;
  float g = gamma[h];
  float gTc = g;
#pragma unroll
  for (int i = 0; i < 7; i++) gTc *= gTc;       // g^128
  float E = 0.f;
  for (int cidx = 0; cidx < NCHUNK; cidx++) {
    float L = carry[(size_t)cidx * NCHAN + ch];
    carry[(size_t)cidx * NCHAN + ch] = E;
    E = gTc * E + L;
  }
}

__global__ __launch_bounds__(256) void scan_p3(const unsigned short* __restrict__ qkv,
                                               unsigned short* __restrict__ gb,
                                               const float* __restrict__ gamma,
                                               const float* __restrict__ carry) {
  int idx = blockIdx.x * 256 + threadIdx.x;
  int ch4 = idx & 2047;
  int chunk = idx >> 11;
  int b = ch4 >> 9;
  int c = (ch4 & 511) * 4;
  float g = gamma[c >> 7];
  float4 Sv = *(const float4*)(carry + (size_t)chunk * NCHAN + b * Cc + c);
  float S[4] = {Sv.x, Sv.y, Sv.z, Sv.w};
  const unsigned short* qb = qkv + ((size_t)(b * Tt + chunk * TCHUNK)) * NQKV + c;
  unsigned short* gp = gb + ((size_t)(b * Tt + chunk * TCHUNK)) * Cc + c;
#pragma unroll 4
  for (int t = 0; t < TCHUNK; t++) {
    const unsigned short* p = qb + (size_t)t * NQKV;
    uint2 qq = *(const uint2*)(p);
    uint2 kk = *(const uint2*)(p + Cc);
    uint2 vv = *(const uint2*)(p + 2 * Cc);
    uint2 gg = *(const uint2*)(gp + (size_t)t * Cc);
    float q0 = bf2f((unsigned short)(qq.x & 0xffff)), q1 = bf2f((unsigned short)(qq.x >> 16));
    float q2 = bf2f((unsigned short)(qq.y & 0xffff)), q3 = bf2f((unsigned short)(qq.y >> 16));
    float k0 = bf2f((unsigned short)(kk.x & 0xffff)), k1 = bf2f((unsigned short)(kk.x >> 16));
    float k2 = bf2f((unsigned short)(kk.y & 0xffff)), k3 = bf2f((unsigned short)(kk.y >> 16));
    float v0 = bf2f((unsigned short)(vv.x & 0xffff)), v1 = bf2f((unsigned short)(vv.x >> 16));
    float v2 = bf2f((unsigned short)(vv.y & 0xffff)), v3 = bf2f((unsigned short)(vv.y >> 16));
    float g0 = bf2f((unsigned short)(gg.x & 0xffff)), g1 = bf2f((unsigned short)(gg.x >> 16));
    float g2 = bf2f((unsigned short)(gg.y & 0xffff)), g3 = bf2f((unsigned short)(gg.y >> 16));
    S[0] = g * S[0] + k0 * v0;
    S[1] = g * S[1] + k1 * v1;
    S[2] = g * S[2] + k2 * v2;
    S[3] = g * S[3] + k3 * v3;
    unsigned short o0 = f2bf(g0 * S[0] * q0);
    unsigned short o1 = f2bf(g1 * S[1] * q1);
    unsigned short o2 = f2bf(g2 * S[2] * q2);
    unsigned short o3 = f2bf(g3 * S[3] * q3);
    *(uint2*)(gp + (size_t)t * Cc) =
        make_uint2((unsigned)o0 | ((unsigned)o1 << 16), (unsigned)o2 | ((unsigned)o3 << 16));
  }
}

// ---------------- LayerNorm over C=2048, in-place on fp32 ----------------
__global__ __launch_bounds__(256) void ln_kernel(float* __restrict__ y,
                                                 const float* __restrict__ w,
                                                 const float* __restrict__ b) {
  float* p = y + (size_t)blockIdx.x * Cc;
  int tid = threadIdx.x;
  float v[8];
  float s = 0.f, sq = 0.f;
#pragma unroll
  for (int i = 0; i < 8; i++) {
    v[i] = p[tid + i * 256];
    s += v[i];
    sq += v[i] * v[i];
  }
#pragma unroll
  for (int o = 32; o > 0; o >>= 1) { s += __shfl_down(s, o); sq += __shfl_down(sq, o); }
  __shared__ float ss[4], ssq[4];
  int wave = tid >> 6, lane = tid & 63;
  if (lane == 0) { ss[wave] = s; ssq[wave] = sq; }
  __syncthreads();
  s = ss[0] + ss[1] + ss[2] + ss[3];
  sq = ssq[0] + ssq[1] + ssq[2] + ssq[3];
  float mu = s * (1.f / (float)Cc);
  float var = fmaxf(sq * (1.f / (float)Cc) - mu * mu, 0.f);
  float rs = rsqrtf(var + 1e-5f);
#pragma unroll
  for (int i = 0; i < 8; i++) {
    int c = tid + i * 256;
    p[c] = (v[i] - mu) * rs * w[c] + b[c];
  }
}

extern "C" void kernel_launch(void* const* d_in, const int* in_sizes, int n_in,
                              void* d_out, int out_size, void* d_ws, size_t ws_size,
                              hipStream_t stream) {
  const float* x      = (const float*)d_in[0];
  const float* Wq     = (const float*)d_in[1];
  const float* Wk     = (const float*)d_in[2];
  const float* Wv     = (const float*)d_in[3];
  const float* Wo     = (const float*)d_in[4];
  const float* conv_w = (const float*)d_in[5];
  const float* conv_b = (const float*)d_in[6];
  const float* gate_w = (const float*)d_in[7];
  const float* gate_b = (const float*)d_in[8];
  const float* ln_w   = (const float*)d_in[9];
  const float* ln_b   = (const float*)d_in[10];
  const float* gamma  = (const float*)d_in[11];

  char* ws = (char*)d_ws;
  const size_t SZ_BTC = (size_t)BT * Cc * 2;     // 64 MB (bf16 [BT, Cc])
  const size_t SZ_W   = (size_t)Cc * Cc * 2;     // 8 MB per weight
  unsigned short* xb   = (unsigned short*)(ws);
  unsigned short* xcb  = (unsigned short*)(ws + SZ_BTC);
  unsigned short* wb   = (unsigned short*)(ws + 2 * SZ_BTC);            // wq|wk|wv|wo|wg
  unsigned short* qkvb = (unsigned short*)(ws + 2 * SZ_BTC + 5 * SZ_W); // [BT, 6144]
  unsigned short* gb   = (unsigned short*)(ws + 2 * SZ_BTC + 5 * SZ_W + 3 * SZ_BTC);
  float* carry         = (float*)(ws + 2 * SZ_BTC + 5 * SZ_W + 4 * SZ_BTC); // 1 MB

  unsigned short* wob = wb + 3 * (size_t)Cc * Cc;
  unsigned short* wgb = wb + 4 * (size_t)Cc * Cc;

  const int nW = Cc * Cc;
  cvt5_kernel<<<5 * nW / 1024, 256, 0, stream>>>(Wq, Wk, Wv, Wo, gate_w, wb);
  conv_kernel<<<(BT / 8) * (Cc / 4) / 256, 256, 0, stream>>>(x, conv_w, conv_b, xb, xcb);

  // fused q/k/v GEMM with l2norm epilogue on q,k
  dim3 gqkv(BT / 256, NQKV / 256);               // 64 x 24 = 1536 blocks (nwg % 8 == 0)
  gemm256<3><<<gqkv, 512, 0, stream>>>(xb, wb, qkvb, nullptr, BT, NQKV, Cc);

  // gate GEMM
  dim3 ggrid(BT / 256, Cc / 256);                // 64 x 8 = 512 blocks
  gemm256<1><<<ggrid, 512, 0, stream>>>(xcb, wgb, gb, gate_b, BT, Cc, Cc);

  // decayed scan + gating (out written in-place over gb)
  scan_p1<<<(NCHUNK * NCHAN / 4) / 256, 256, 0, stream>>>(qkvb, gamma, carry);
  scan_p2<<<NCHAN / 256, 256, 0, stream>>>(carry, gamma);
  scan_p3<<<(NCHUNK * NCHAN / 4) / 256, 256, 0, stream>>>(qkvb, gb, gamma, carry);

  // y = out @ Wo^T  (fp32 into d_out), then LayerNorm in place
  gemm256<2><<<ggrid, 512, 0, stream>>>(gb, wob, d_out, nullptr, BT, Cc, Cc);
  ln_kernel<<<BT, 256, 0, stream>>>((float*)d_out, ln_w, ln_b);
}

// Round 4
// 1153.704 us; speedup vs baseline: 1.0572x; 1.0572x over previous
//
#include <hip/hip_runtime.h>
#include <cstdint>

// Problem constants
#define Bb 4
#define Tt 4096
#define Cc 2048
#define Hh 16
#define Dh 128
#define BT (Bb * Tt)            // 16384 rows
#define NCHUNK 32
#define TCHUNK 128              // NCHUNK*TCHUNK == Tt
#define NCHAN (Bb * Cc)         // 8192 scan channels
#define NQKV 6144               // 3*Cc

typedef __bf16 bf16x8 __attribute__((ext_vector_type(8)));
typedef float f32x4 __attribute__((ext_vector_type(4)));
typedef unsigned short u16x8 __attribute__((ext_vector_type(8)));

__device__ __forceinline__ float bf2f(unsigned short u) {
  return __uint_as_float(((unsigned)u) << 16);
}
__device__ __forceinline__ unsigned short f2bf(float f) {
  unsigned u = __float_as_uint(f);
  u = u + 0x7fffu + ((u >> 16) & 1u);   // RNE
  return (unsigned short)(u >> 16);
}

// async global->LDS, 16B per lane; lds must be wave-uniform (HW writes base + lane*16)
__device__ __forceinline__ void async_copy16(void* lds, const void* gmem) {
  auto* lp = (__attribute__((address_space(3))) unsigned int*)(unsigned)(uintptr_t)(lds);
  auto* gp = (const __attribute__((address_space(1))) unsigned int*)(uintptr_t)(gmem);
  __builtin_amdgcn_global_load_lds(gp, lp, 16, 0, 0);
}

// ---------------- fp32 -> bf16 convert: 5 weight matrices into one packed buffer ----
// dst layout: [wq | wk | wv | wo | wg], each nW = Cc*Cc elements
__global__ __launch_bounds__(256) void cvt5_kernel(const float* __restrict__ Wq,
                                                   const float* __restrict__ Wk,
                                                   const float* __restrict__ Wv,
                                                   const float* __restrict__ Wo,
                                                   const float* __restrict__ Wg,
                                                   unsigned short* __restrict__ dst) {
  size_t idx4 = ((size_t)blockIdx.x * 256 + threadIdx.x) * 4;
  int region = (int)(idx4 >> 22);               // nW = 2^22
  size_t off = idx4 & ((1u << 22) - 1);
  const float* src;
  switch (region) {
    case 0: src = Wq; break;
    case 1: src = Wk; break;
    case 2: src = Wv; break;
    case 3: src = Wo; break;
    default: src = Wg; break;
  }
  float4 v = *(const float4*)(src + off);
  unsigned r0 = (unsigned)f2bf(v.x) | ((unsigned)f2bf(v.y) << 16);
  unsigned r1 = (unsigned)f2bf(v.z) | ((unsigned)f2bf(v.w) << 16);
  *(uint2*)(dst + idx4) = make_uint2(r0, r1);
}

// ---------------- depthwise causal conv K=4 + SiLU + x->bf16 ----------------
__global__ __launch_bounds__(256) void conv_kernel(const float* __restrict__ x,
                                                   const float* __restrict__ cw,
                                                   const float* __restrict__ cb,
                                                   unsigned short* __restrict__ xb,
                                                   unsigned short* __restrict__ xcb) {
  int idx = blockIdx.x * 256 + threadIdx.x;
  int cg = idx & 511;                 // Cc/4
  int rg = idx >> 9;                  // row group over BT/8
  int c = cg * 4;
  size_t bt0 = (size_t)rg * 8;
  int t0 = (int)(bt0 & (Tt - 1));
  const float* xp = x + bt0 * Cc + c;

  float4 w4[4];
#pragma unroll
  for (int u = 0; u < 4; u++) w4[u] = *(const float4*)(cw + (size_t)(c + u) * 4);
  float4 bias = *(const float4*)(cb + c);
  const float* bs = (const float*)&bias;

  float xr[11][4];                    // rows t0-3..t0+7
  if (t0 != 0) {
#pragma unroll
    for (int j = 0; j < 3; j++) {
      float4 p = *(const float4*)(xp - (size_t)(3 - j) * Cc);
      xr[j][0] = p.x; xr[j][1] = p.y; xr[j][2] = p.z; xr[j][3] = p.w;
    }
  } else {
#pragma unroll
    for (int j = 0; j < 3; j++)
#pragma unroll
      for (int u = 0; u < 4; u++) xr[j][u] = 0.f;
  }
#pragma unroll
  for (int i = 0; i < 8; i++) {
    float4 p = *(const float4*)(xp + (size_t)i * Cc);
    xr[3 + i][0] = p.x; xr[3 + i][1] = p.y; xr[3 + i][2] = p.z; xr[3 + i][3] = p.w;
    unsigned a0 = (unsigned)f2bf(p.x) | ((unsigned)f2bf(p.y) << 16);
    unsigned a1 = (unsigned)f2bf(p.z) | ((unsigned)f2bf(p.w) << 16);
    *(uint2*)(xb + (bt0 + i) * Cc + c) = make_uint2(a0, a1);
  }
#pragma unroll
  for (int i = 0; i < 8; i++) {
    unsigned short o[4];
#pragma unroll
    for (int u = 0; u < 4; u++) {
      const float* wf = (const float*)&w4[u];
      float a = bs[u];
#pragma unroll
      for (int j = 0; j < 4; j++) a += wf[3 - j] * xr[3 + i - j][u];
      float sig = 1.f / (1.f + expf(-a));
      o[u] = f2bf(a * sig);
    }
    unsigned q0 = (unsigned)o[0] | ((unsigned)o[1] << 16);
    unsigned q1 = (unsigned)o[2] | ((unsigned)o[3] << 16);
    *(uint2*)(xcb + (bt0 + i) * Cc + c) = make_uint2(q0, q1);
  }
}

// ---------------- 256x256-tile bf16 GEMM: C[M,N] = A[M,K] * B[N,K]^T ----------------
// 8 waves (2M x 4N), BK=32, 4-slot LDS ring staging t+2 while computing t.
// ONE barrier per K-tile + within-tile read-ahead:
//   tile t: issue 12 ds_reads (afA m0-3, bf n0-3 | afB m4-7) of slot t; stage t+2;
//           lgkmcnt(4)  -> afA+bf ready, afB's 4 in flight under MFMA-A
//           MFMA A (16); lgkmcnt(0) (afB long done); MFMA B (16);
//           vmcnt(4) [t+1 fully landed, t+2 in flight]; s_barrier
// Ordering pinned: DS completes in issue order; issue order pinned via sched_barrier(0);
// every wait is asm w/ memory clobber (loads can't hoist past), sched_barrier(0) after
// each wait fences MFMA hoisting (rule #18). Ring safety: staging writes slot (t+2)&3 =
// slot (t-2)&3 whose reads finished before the end-of-(t-1) barrier; per-wave vmcnt(4)
// before each tile-end barrier guarantees slot t+1 fully staged chip-wide.
// Bank swizzle (measured 0 conflicts): slot s of row r holds logical slot s ^ ((r>>1)&3),
// pre-swizzled global SOURCE + swizzled ds_read offsets (both-sides, rule #21).
// EPI: 1 = sigmoid(acc + bias[col]) bf16 store, 2 = fp32 store,
//      3 = fused qkv: bf16 store; rows l2-normalized per 128-col head group when n0 < 2*Cc
template <int EPI>
__global__ __launch_bounds__(512, 2) void gemm256(const unsigned short* __restrict__ A,
                                                  const unsigned short* __restrict__ B,
                                                  void* __restrict__ C,
                                                  const float* __restrict__ bias,
                                                  int M, int N, int K) {
  __shared__ unsigned short As[4][256 * 32];   // 64 KiB
  __shared__ unsigned short Bs[4][256 * 32];   // 64 KiB
  __shared__ float rowsq[256][4];              // 4 KiB

  const int tid = threadIdx.x;
  const int w = tid >> 6;        // wave 0..7
  const int lane = tid & 63;

  // T1: XCD-aware block swizzle (nwg % 8 == 0 for all our launches)
  const int nwg = gridDim.x * gridDim.y;
  const int flat = blockIdx.y * gridDim.x + blockIdx.x;
  const int cpx = nwg >> 3;
  const int swz = (flat & 7) * cpx + (flat >> 3);
  const int bx = swz % gridDim.x;
  const int by = swz / gridDim.x;
  const int m0 = bx * 256;
  const int n0 = by * 256;

  const int wr = w >> 2;         // 0..1 -> 128-row half
  const int wc = w & 3;          // 0..3 -> 64-col strip

  // ---- staging addresses (2 issues/thread per matrix per K-tile, 16 rows/issue) ----
  const int srow = lane >> 2;                                   // 0..15 within group
  const int scol = (((lane & 3) ^ ((lane >> 3) & 3)) << 3);     // swizzled source col (elems)
  const int r16 = w * 2;                                        // row-group of issue 0
  const unsigned short* Ag0 = A + (size_t)(m0 + r16 * 16 + srow) * K + scol;
  const unsigned short* Ag1 = Ag0 + (size_t)16 * K;
  const unsigned short* Bg0 = B + (size_t)(n0 + r16 * 16 + srow) * K + scol;
  const unsigned short* Bg1 = Bg0 + (size_t)16 * K;

  // ---- fragment read addressing (same swizzle) ----
  const int frow = lane & 15;
  const int cbs = ((((lane >> 4) << 4) ^ (((frow >> 1) & 3) << 4)) >> 1);  // short offset in row

  f32x4 acc[8][4] = {};
  const int NT = K >> 5;

  // prologue: stage K-tiles 0 and 1 fully; wait tile 0 (leave tile 1 in flight)
  {
    unsigned short* dA0 = &As[0][r16 * 512];
    unsigned short* dB0 = &Bs[0][r16 * 512];
    async_copy16(dA0, Ag0); async_copy16(dA0 + 512, Ag1);
    async_copy16(dB0, Bg0); async_copy16(dB0 + 512, Bg1);
    unsigned short* dA1 = &As[1][r16 * 512];
    unsigned short* dB1 = &Bs[1][r16 * 512];
    async_copy16(dA1, Ag0 + 32); async_copy16(dA1 + 512, Ag1 + 32);
    async_copy16(dB1, Bg0 + 32); async_copy16(dB1 + 512, Bg1 + 32);
  }
  asm volatile("s_waitcnt vmcnt(4)" ::: "memory");
  __builtin_amdgcn_s_barrier();

  for (int t = 0; t < NT; ++t) {
    const int slot = t & 3;
    const unsigned short* as = &As[slot][0] + wr * 4096 + cbs;
    const unsigned short* bsb = &Bs[slot][0] + wc * 2048 + cbs;
    const bool pf = (t + 2 < NT);
    const int kpf = (t + 2) << 5;

    bf16x8 afA[4], afB[4], bf[4];
    // issue group 1: afA + bf (these 8 are the oldest in the DS queue)
#pragma unroll
    for (int m = 0; m < 4; m++)
      afA[m] = __builtin_bit_cast(bf16x8, *(const u16x8*)(as + (m * 16 + frow) * 32));
#pragma unroll
    for (int n = 0; n < 4; n++)
      bf[n] = __builtin_bit_cast(bf16x8, *(const u16x8*)(bsb + (n * 16 + frow) * 32));
    __builtin_amdgcn_sched_barrier(0);   // pin: group 1 issued before group 2
    // issue group 2: afB (stay in flight under MFMA A)
#pragma unroll
    for (int m = 0; m < 4; m++)
      afB[m] = __builtin_bit_cast(bf16x8, *(const u16x8*)(as + ((m + 4) * 16 + frow) * 32));
    __builtin_amdgcn_sched_barrier(0);   // pin: reads before staging/waits
    // stage tile t+2 into slot (t+2)&3 (== slot (t-2)&3, reads finished last barrier)
    if (pf) {
      unsigned short* dA = &As[(t + 2) & 3][r16 * 512];
      unsigned short* dB = &Bs[(t + 2) & 3][r16 * 512];
      async_copy16(dA, Ag0 + kpf); async_copy16(dA + 512, Ag1 + kpf);
      async_copy16(dB, Bg0 + kpf); async_copy16(dB + 512, Bg1 + kpf);
    }
    asm volatile("s_waitcnt lgkmcnt(4)" ::: "memory");   // afA+bf ready; afB in flight
    __builtin_amdgcn_sched_barrier(0);
    __builtin_amdgcn_s_setprio(1);
#pragma unroll
    for (int m = 0; m < 4; m++)
#pragma unroll
      for (int n = 0; n < 4; n++)
        acc[m][n] = __builtin_amdgcn_mfma_f32_16x16x32_bf16(afA[m], bf[n], acc[m][n], 0, 0, 0);
    __builtin_amdgcn_s_setprio(0);
    asm volatile("s_waitcnt lgkmcnt(0)" ::: "memory");   // afB done (completed under MFMA A)
    __builtin_amdgcn_sched_barrier(0);
    __builtin_amdgcn_s_setprio(1);
#pragma unroll
    for (int m = 0; m < 4; m++)
#pragma unroll
      for (int n = 0; n < 4; n++)
        acc[m + 4][n] = __builtin_amdgcn_mfma_f32_16x16x32_bf16(afB[m], bf[n], acc[m + 4][n], 0, 0, 0);
    __builtin_amdgcn_s_setprio(0);
    // tile boundary: ensure t+1 fully landed; keep t+2's 4 loads in flight
    if (pf) asm volatile("s_waitcnt vmcnt(4)" ::: "memory");
    else    asm volatile("s_waitcnt vmcnt(0)" ::: "memory");
    __builtin_amdgcn_s_barrier();
  }

  // ---------------- epilogue ----------------
  const int crow0 = (lane >> 4) * 4;
  const int ccol = lane & 15;

  float inv[8][4];
  const bool donorm = (EPI == 3) && (n0 < 2 * Cc);
  if (donorm) {
#pragma unroll
    for (int m = 0; m < 8; m++) {
#pragma unroll
      for (int r = 0; r < 4; r++) {
        float sq = 0.f;
#pragma unroll
        for (int n = 0; n < 4; n++) { float v = acc[m][n][r]; sq += v * v; }
        sq += __shfl_xor(sq, 1);
        sq += __shfl_xor(sq, 2);
        sq += __shfl_xor(sq, 4);
        sq += __shfl_xor(sq, 8);
        if (ccol == 0) rowsq[wr * 128 + m * 16 + crow0 + r][wc] = sq;
      }
    }
    __syncthreads();
#pragma unroll
    for (int m = 0; m < 8; m++)
#pragma unroll
      for (int r = 0; r < 4; r++) {
        int rloc = wr * 128 + m * 16 + crow0 + r;
        int g2 = (wc >> 1) * 2;
        float s = rowsq[rloc][g2] + rowsq[rloc][g2 + 1];
        inv[m][r] = 1.f / fmaxf(sqrtf(s), 1e-12f);
      }
  }

#pragma unroll
  for (int m = 0; m < 8; m++) {
#pragma unroll
    for (int n = 0; n < 4; n++) {
      int col = n0 + wc * 64 + n * 16 + ccol;
      float bv = (EPI == 1) ? bias[col] : 0.f;
#pragma unroll
      for (int r = 0; r < 4; r++) {
        int row = m0 + wr * 128 + m * 16 + crow0 + r;
        float v = acc[m][n][r];
        if (EPI == 1) v = 1.f / (1.f + expf(-(v + bv)));
        if (donorm) v *= inv[m][r];
        if (EPI == 2)
          ((float*)C)[(size_t)row * N + col] = v;
        else
          ((unsigned short*)C)[(size_t)row * N + col] = f2bf(v);
      }
    }
  }
}

// ---------------- chunked decayed scan (4 channels / thread) ----------------
__global__ __launch_bounds__(256) void scan_p1(const unsigned short* __restrict__ qkv,
                                               const float* __restrict__ gamma,
                                               float* __restrict__ carry) {
  int idx = blockIdx.x * 256 + threadIdx.x;     // [0, NCHUNK*NCHAN/4)
  int ch4 = idx & 2047;                         // NCHAN/4
  int chunk = idx >> 11;
  int b = ch4 >> 9;
  int c = (ch4 & 511) * 4;
  float g = gamma[c >> 7];
  const unsigned short* kb = qkv + ((size_t)(b * Tt + chunk * TCHUNK)) * NQKV + Cc + c;
  float L[4] = {0.f, 0.f, 0.f, 0.f};
#pragma unroll 4
  for (int t = 0; t < TCHUNK; t++) {
    const unsigned short* p = kb + (size_t)t * NQKV;
    uint2 kk = *(const uint2*)(p);
    uint2 vv = *(const uint2*)(p + Cc);
    L[0] = g * L[0] + bf2f((unsigned short)(kk.x & 0xffff)) * bf2f((unsigned short)(vv.x & 0xffff));
    L[1] = g * L[1] + bf2f((unsigned short)(kk.x >> 16))    * bf2f((unsigned short)(vv.x >> 16));
    L[2] = g * L[2] + bf2f((unsigned short)(kk.y & 0xffff)) * bf2f((unsigned short)(vv.y & 0xffff));
    L[3] = g * L[3] + bf2f((unsigned short)(kk.y >> 16))    * bf2f((unsigned short)(vv.y >> 16));
  }
  *(float4*)(carry + (size_t)chunk * NCHAN + b * Cc + c) = make_float4(L[0], L[1], L[2], L[3]);
}

__global__ __launch_bounds__(256) void scan_p2(float* __restrict__ carry,
                                               const float* __restrict__ gamma) {
  int ch = blockIdx.x * 256 + threadIdx.x;      // [0, NCHAN)
  int h = (ch & (Cc - 1)) >> 7;
  float g = gamma[h];
  float gTc = g;
#pragma unroll
  for (int i = 0; i < 7; i++) gTc *= gTc;       // g^128
  float E = 0.f;
  for (int cidx = 0; cidx < NCHUNK; cidx++) {
    float L = carry[(size_t)cidx * NCHAN + ch];
    carry[(size_t)cidx * NCHAN + ch] = E;
    E = gTc * E + L;
  }
}

__global__ __launch_bounds__(256) void scan_p3(const unsigned short* __restrict__ qkv,
                                               unsigned short* __restrict__ gb,
                                               const float* __restrict__ gamma,
                                               const float* __restrict__ carry) {
  int idx = blockIdx.x * 256 + threadIdx.x;
  int ch4 = idx & 2047;
  int chunk = idx >> 11;
  int b = ch4 >> 9;
  int c = (ch4 & 511) * 4;
  float g = gamma[c >> 7];
  float4 Sv = *(const float4*)(carry + (size_t)chunk * NCHAN + b * Cc + c);
  float S[4] = {Sv.x, Sv.y, Sv.z, Sv.w};
  const unsigned short* qb = qkv + ((size_t)(b * Tt + chunk * TCHUNK)) * NQKV + c;
  unsigned short* gp = gb + ((size_t)(b * Tt + chunk * TCHUNK)) * Cc + c;
#pragma unroll 4
  for (int t = 0; t < TCHUNK; t++) {
    const unsigned short* p = qb + (size_t)t * NQKV;
    uint2 qq = *(const uint2*)(p);
    uint2 kk = *(const uint2*)(p + Cc);
    uint2 vv = *(const uint2*)(p + 2 * Cc);
    uint2 gg = *(const uint2*)(gp + (size_t)t * Cc);
    float q0 = bf2f((unsigned short)(qq.x & 0xffff)), q1 = bf2f((unsigned short)(qq.x >> 16));
    float q2 = bf2f((unsigned short)(qq.y & 0xffff)), q3 = bf2f((unsigned short)(qq.y >> 16));
    float k0 = bf2f((unsigned short)(kk.x & 0xffff)), k1 = bf2f((unsigned short)(kk.x >> 16));
    float k2 = bf2f((unsigned short)(kk.y & 0xffff)), k3 = bf2f((unsigned short)(kk.y >> 16));
    float v0 = bf2f((unsigned short)(vv.x & 0xffff)), v1 = bf2f((unsigned short)(vv.x >> 16));
    float v2 = bf2f((unsigned short)(vv.y & 0xffff)), v3 = bf2f((unsigned short)(vv.y >> 16));
    float g0 = bf2f((unsigned short)(gg.x & 0xffff)), g1 = bf2f((unsigned short)(gg.x >> 16));
    float g2 = bf2f((unsigned short)(gg.y & 0xffff)), g3 = bf2f((unsigned short)(gg.y >> 16));
    S[0] = g * S[0] + k0 * v0;
    S[1] = g * S[1] + k1 * v1;
    S[2] = g * S[2] + k2 * v2;
    S[3] = g * S[3] + k3 * v3;
    unsigned short o0 = f2bf(g0 * S[0] * q0);
    unsigned short o1 = f2bf(g1 * S[1] * q1);
    unsigned short o2 = f2bf(g2 * S[2] * q2);
    unsigned short o3 = f2bf(g3 * S[3] * q3);
    *(uint2*)(gp + (size_t)t * Cc) =
        make_uint2((unsigned)o0 | ((unsigned)o1 << 16), (unsigned)o2 | ((unsigned)o3 << 16));
  }
}

// ---------------- LayerNorm over C=2048, in-place on fp32 ----------------
__global__ __launch_bounds__(256) void ln_kernel(float* __restrict__ y,
                                                 const float* __restrict__ w,
                                                 const float* __restrict__ b) {
  float* p = y + (size_t)blockIdx.x * Cc;
  int tid = threadIdx.x;
  float v[8];
  float s = 0.f, sq = 0.f;
#pragma unroll
  for (int i = 0; i < 8; i++) {
    v[i] = p[tid + i * 256];
    s += v[i];
    sq += v[i] * v[i];
  }
#pragma unroll
  for (int o = 32; o > 0; o >>= 1) { s += __shfl_down(s, o); sq += __shfl_down(sq, o); }
  __shared__ float ss[4], ssq[4];
  int wave = tid >> 6, lane = tid & 63;
  if (lane == 0) { ss[wave] = s; ssq[wave] = sq; }
  __syncthreads();
  s = ss[0] + ss[1] + ss[2] + ss[3];
  sq = ssq[0] + ssq[1] + ssq[2] + ssq[3];
  float mu = s * (1.f / (float)Cc);
  float var = fmaxf(sq * (1.f / (float)Cc) - mu * mu, 0.f);
  float rs = rsqrtf(var + 1e-5f);
#pragma unroll
  for (int i = 0; i < 8; i++) {
    int c = tid + i * 256;
    p[c] = (v[i] - mu) * rs * w[c] + b[c];
  }
}

extern "C" void kernel_launch(void* const* d_in, const int* in_sizes, int n_in,
                              void* d_out, int out_size, void* d_ws, size_t ws_size,
                              hipStream_t stream) {
  const float* x      = (const float*)d_in[0];
  const float* Wq     = (const float*)d_in[1];
  const float* Wk     = (const float*)d_in[2];
  const float* Wv     = (const float*)d_in[3];
  const float* Wo     = (const float*)d_in[4];
  const float* conv_w = (const float*)d_in[5];
  const float* conv_b = (const float*)d_in[6];
  const float* gate_w = (const float*)d_in[7];
  const float* gate_b = (const float*)d_in[8];
  const float* ln_w   = (const float*)d_in[9];
  const float* ln_b   = (const float*)d_in[10];
  const float* gamma  = (const float*)d_in[11];

  char* ws = (char*)d_ws;
  const size_t SZ_BTC = (size_t)BT * Cc * 2;     // 64 MB (bf16 [BT, Cc])
  const size_t SZ_W   = (size_t)Cc * Cc * 2;     // 8 MB per weight
  unsigned short* xb   = (unsigned short*)(ws);
  unsigned short* xcb  = (unsigned short*)(ws + SZ_BTC);
  unsigned short* wb   = (unsigned short*)(ws + 2 * SZ_BTC);            // wq|wk|wv|wo|wg
  unsigned short* qkvb = (unsigned short*)(ws + 2 * SZ_BTC + 5 * SZ_W); // [BT, 6144]
  unsigned short* gb   = (unsigned short*)(ws + 2 * SZ_BTC + 5 * SZ_W + 3 * SZ_BTC);
  float* carry         = (float*)(ws + 2 * SZ_BTC + 5 * SZ_W + 4 * SZ_BTC); // 1 MB

  unsigned short* wob = wb + 3 * (size_t)Cc * Cc;
  unsigned short* wgb = wb + 4 * (size_t)Cc * Cc;

  const int nW = Cc * Cc;
  cvt5_kernel<<<5 * nW / 1024, 256, 0, stream>>>(Wq, Wk, Wv, Wo, gate_w, wb);
  conv_kernel<<<(BT / 8) * (Cc / 4) / 256, 256, 0, stream>>>(x, conv_w, conv_b, xb, xcb);

  // fused q/k/v GEMM with l2norm epilogue on q,k
  dim3 gqkv(BT / 256, NQKV / 256);               // 64 x 24 = 1536 blocks (nwg % 8 == 0)
  gemm256<3><<<gqkv, 512, 0, stream>>>(xb, wb, qkvb, nullptr, BT, NQKV, Cc);

  // gate GEMM
  dim3 ggrid(BT / 256, Cc / 256);                // 64 x 8 = 512 blocks
  gemm256<1><<<ggrid, 512, 0, stream>>>(xcb, wgb, gb, gate_b, BT, Cc, Cc);

  // decayed scan + gating (out written in-place over gb)
  scan_p1<<<(NCHUNK * NCHAN / 4) / 256, 256, 0, stream>>>(qkvb, gamma, carry);
  scan_p2<<<NCHAN / 256, 256, 0, stream>>>(carry, gamma);
  scan_p3<<<(NCHUNK * NCHAN / 4) / 256, 256, 0, stream>>>(qkvb, gb, gamma, carry);

  // y = out @ Wo^T  (fp32 into d_out), then LayerNorm in place
  gemm256<2><<<ggrid, 512, 0, stream>>>(gb, wob, d_out, nullptr, BT, Cc, Cc);
  ln_kernel<<<BT, 256, 0, stream>>>((float*)d_out, ln_w, ln_b);
}